// Round 7
// baseline (463.799 us; speedup 1.0000x reference)
//
#include <hip/hip_runtime.h>
#include <math.h>

typedef _Float16 f16;
typedef __attribute__((ext_vector_type(8))) _Float16 half8;
typedef __attribute__((ext_vector_type(4))) float f32x4;
typedef __attribute__((ext_vector_type(4))) int i32x4;

#define NEXP 64
#define TMR 32          // fast-kernel rows per block (grid 1024)
#define TM 64           // fallback rows per block
#define L_STRIDE 132

__device__ __forceinline__ float softplus_f(float x) {
    return fmaxf(x, 0.0f) + log1pf(expf(-fabsf(x)));
}

__device__ __forceinline__ void cvt_split(const float4 a, const float4 b,
                                          half8& hv, half8& lv) {
    const float vv[8] = {a.x, a.y, a.z, a.w, b.x, b.y, b.z, b.w};
#pragma unroll
    for (int j = 0; j < 8; ++j) {
        const f16 h = (f16)vv[j];
        hv[j] = h;
        lv[j] = (f16)((vv[j] - (float)h) * 4096.0f);
    }
}

// intra-wave fragment permute: dst lane takes all 4 dwords from src lane s.
// ds_bpermute crossbar: no LDS space, no bank conflicts, no barrier.
__device__ __forceinline__ half8 shfl_frag(half8 v, int s) {
    union { half8 h; i32x4 i; } u;
    u.h = v;
#pragma unroll
    for (int j = 0; j < 4; ++j) u.i[j] = __shfl(u.i[j], s, 64);
    return u.h;
}

// ---------------- pre-kernel: split W (route|noise) into f16 hi/lo planes ----
// ws layout (f16 units): [kc][plane(2)][q(4)][col(128)][8]   (16 KB per kc)
__global__ void wsplit_kernel(const float* __restrict__ Wr,
                              const float* __restrict__ Wn,
                              f16* __restrict__ ws, int D) {
    const int per_col = D >> 3;
    const int t = blockIdx.x * blockDim.x + threadIdx.x;
    const int col = t / per_col;
    const int k0  = (t - col * per_col) * 8;
    if (col >= 128) return;
    const float* src = (col < NEXP) ? &Wr[(size_t)col * D] : &Wn[(size_t)(col - NEXP) * D];
    const float4 v0 = *(const float4*)&src[k0];
    const float4 v1 = *(const float4*)&src[k0 + 4];
    half8 hi, lo;
    cvt_split(v0, v1, hi, lo);
    const int kc = k0 >> 5, q = (k0 >> 3) & 3;
    const size_t base = (size_t)kc * 8192 + (size_t)q * 1024 + (size_t)col * 8;
    *(half8*)&ws[base]        = hi;
    *(half8*)&ws[base + 4096] = lo;
}

// ---------------- main kernel: barrier-free per-wave register pipeline -------
// Diagnosis (rounds 0/2/4/5): the LDS-staging + s_barrier apparatus costs
// ~4000 stall cycles per K-chunk no matter the sync flavor or buffer depth
// (m233's 2-phase structural overhead). This kernel deletes it: NO s_barrier
// and NO LDS in the K-loop. Each wave loads its own B fragments straight from
// the L1/L2-hot ws workspace (ws layout == fragment layout), loads its own 16
// x-rows coalesced and transposes them with 8 ds_bpermute shuffles (fixed
// intra-wave permutation), and runs a 2-deep register pipeline via unroll-2
// with named E/O sets: x reloaded at distance 2 (HBM cover ~2 bodies), B at
// distance 2 into the just-consumed set (cover ~1.3 bodies). sched_barrier(0)
// fences pin issue order (round-3 lesson); all waitcnts are compiler-emitted
// counted waits (no barrier -> no vmcnt(0) drain anywhere in the loop).
__global__ __launch_bounds__(256, 2)
void router_mfma_kernel(const float* __restrict__ x,
                        const f16* __restrict__ wsW,
                        const float* __restrict__ br,
                        const float* __restrict__ bn,
                        const float* __restrict__ eps,
                        float* __restrict__ out,
                        int N, int D) {
    __shared__ struct {
        float L[TMR][L_STRIDE];                       // 16.9 KB
        float p1[TMR], p2[TMR];
        int   i1[TMR], i2[TMR];
    } ep;

    const int tid  = threadIdx.x;
    const int lane = tid & 63;
    const int w    = tid >> 6;
    const int rowbase = blockIdx.x * TMR;
    const int wr = w & 1, wc = w >> 1;     // wave tile: 16 rows x 64 cols
    const int quad = lane >> 4;
    const int l16  = lane & 15;
    // shuffle source for the x transpose: frag lane (quad,l16) pulls from
    // load lane ((l16)<<2)|quad  (load lane s holds row s>>2, floats (s&3)*8..)
    const int shsrc = (l16 << 2) | quad;

    f32x4 accM[4], accC[4];
#pragma unroll
    for (int j = 0; j < 4; ++j) {
        accM[j] = (f32x4){0.f, 0.f, 0.f, 0.f};
        accC[j] = (f32x4){0.f, 0.f, 0.f, 0.f};
    }

    // x load mapping: lane reads row wr*16 + (lane>>2), floats (lane&3)*8..+7
    // of each 32-float chunk -> 4 consecutive lanes = 128B contiguous.
    const float* xp = x + (size_t)(rowbase + wr * 16 + (lane >> 2)) * D + (lane & 3) * 8;
    // B source (fragment layout directly): col = wc*64 + ct*16 + l16.
    const f16* wsB = wsW + quad * 1024 + (size_t)(wc * 64 + l16) * 8;

    const int nkc = D >> 5;   // 64 (even; host guards D==2048)

    // ---- prologue: x(0)->E, x(1)->O (oldest in queue), then B(0)->E, B(1)->O
    float4 xE0 = *(const float4*)&xp[0];
    float4 xE1 = *(const float4*)&xp[4];
    float4 xO0 = *(const float4*)&xp[32];
    float4 xO1 = *(const float4*)&xp[36];
    __builtin_amdgcn_sched_barrier(0);
    half8 bE0 = *(const half8*)&wsB[0];
    half8 bE1 = *(const half8*)&wsB[128];
    half8 bE2 = *(const half8*)&wsB[256];
    half8 bE3 = *(const half8*)&wsB[384];
    half8 bE4 = *(const half8*)&wsB[4096];
    half8 bE5 = *(const half8*)&wsB[4224];
    half8 bE6 = *(const half8*)&wsB[4352];
    half8 bE7 = *(const half8*)&wsB[4480];
    half8 bO0 = *(const half8*)&wsB[8192];
    half8 bO1 = *(const half8*)&wsB[8192 + 128];
    half8 bO2 = *(const half8*)&wsB[8192 + 256];
    half8 bO3 = *(const half8*)&wsB[8192 + 384];
    half8 bO4 = *(const half8*)&wsB[8192 + 4096];
    half8 bO5 = *(const half8*)&wsB[8192 + 4224];
    half8 bO6 = *(const half8*)&wsB[8192 + 4352];
    half8 bO7 = *(const half8*)&wsB[8192 + 4480];
    __builtin_amdgcn_sched_barrier(0);

#define KBODY(KC, XA0, XA1, B0, B1, B2, B3, B4, B5, B6, B7)                    \
    {                                                                          \
        half8 hv, lv;                                                          \
        cvt_split(XA0, XA1, hv, lv);       /* waits only on this x set */      \
        __builtin_amdgcn_sched_barrier(0);                                     \
        if ((KC) + 2 < nkc) {              /* x(KC+2): ~2 bodies of cover */   \
            XA0 = *(const float4*)&xp[((KC) + 2) * 32];                        \
            XA1 = *(const float4*)&xp[((KC) + 2) * 32 + 4];                    \
        }                                                                      \
        __builtin_amdgcn_sched_barrier(0);                                     \
        const half8 ah = shfl_frag(hv, shsrc);                                 \
        const half8 al = shfl_frag(lv, shsrc);                                 \
        __builtin_amdgcn_sched_barrier(0);                                     \
        accM[0] = __builtin_amdgcn_mfma_f32_16x16x32_f16(ah, B0, accM[0], 0, 0, 0); \
        accC[0] = __builtin_amdgcn_mfma_f32_16x16x32_f16(al, B0, accC[0], 0, 0, 0); \
        accC[0] = __builtin_amdgcn_mfma_f32_16x16x32_f16(ah, B4, accC[0], 0, 0, 0); \
        accM[1] = __builtin_amdgcn_mfma_f32_16x16x32_f16(ah, B1, accM[1], 0, 0, 0); \
        accC[1] = __builtin_amdgcn_mfma_f32_16x16x32_f16(al, B1, accC[1], 0, 0, 0); \
        accC[1] = __builtin_amdgcn_mfma_f32_16x16x32_f16(ah, B5, accC[1], 0, 0, 0); \
        accM[2] = __builtin_amdgcn_mfma_f32_16x16x32_f16(ah, B2, accM[2], 0, 0, 0); \
        accC[2] = __builtin_amdgcn_mfma_f32_16x16x32_f16(al, B2, accC[2], 0, 0, 0); \
        accC[2] = __builtin_amdgcn_mfma_f32_16x16x32_f16(ah, B6, accC[2], 0, 0, 0); \
        accM[3] = __builtin_amdgcn_mfma_f32_16x16x32_f16(ah, B3, accM[3], 0, 0, 0); \
        accC[3] = __builtin_amdgcn_mfma_f32_16x16x32_f16(al, B3, accC[3], 0, 0, 0); \
        accC[3] = __builtin_amdgcn_mfma_f32_16x16x32_f16(ah, B7, accC[3], 0, 0, 0); \
        __builtin_amdgcn_sched_barrier(0);                                     \
        if ((KC) + 2 < nkc) {              /* B(KC+2) into freed set */        \
            const f16* bp = wsB + (size_t)((KC) + 2) * 8192;                   \
            B0 = *(const half8*)&bp[0];                                        \
            B1 = *(const half8*)&bp[128];                                      \
            B2 = *(const half8*)&bp[256];                                      \
            B3 = *(const half8*)&bp[384];                                      \
            B4 = *(const half8*)&bp[4096];                                     \
            B5 = *(const half8*)&bp[4224];                                     \
            B6 = *(const half8*)&bp[4352];                                     \
            B7 = *(const half8*)&bp[4480];                                     \
        }                                                                      \
        __builtin_amdgcn_sched_barrier(0);                                     \
    }

    for (int kc = 0; kc < nkc; kc += 2) {
        KBODY(kc,     xE0, xE1, bE0, bE1, bE2, bE3, bE4, bE5, bE6, bE7)
        KBODY(kc + 1, xO0, xO1, bO0, bO1, bO2, bO3, bO4, bO5, bO6, bO7)
    }
#undef KBODY

    // ---- combine accs + bias -> logits in LDS (C/D: col=lane&15, row=quad*4+rg)
    {
        const float* bias = wc ? bn : br;   // wave-uniform plane select
        const int row = wr * 16 + quad * 4;
#pragma unroll
        for (int ct = 0; ct < 4; ++ct) {
            const int col = wc * 64 + ct * 16 + l16;
            const float bcol = bias[ct * 16 + l16];
#pragma unroll
            for (int rg = 0; rg < 4; ++rg)
                ep.L[row + rg][col] =
                    accM[ct][rg] + accC[ct][rg] * (1.0f / 4096.0f) + bcol;
        }
    }
    __syncthreads();

    // ---- noisy logits in-place over cols 0..63 (32 rows x 64 cols = 2048)
#pragma unroll
    for (int t = 0; t < 2; ++t) {
        const int f   = tid * 4 + t * 1024;
        const int row = f >> 6;
        const int e0  = f & 63;
        const float4 ev = *(const float4*)&eps[(size_t)(rowbase + row) * NEXP + e0];
        const float evs[4] = {ev.x, ev.y, ev.z, ev.w};
#pragma unroll
        for (int j = 0; j < 4; ++j) {
            const float lg = ep.L[row][e0 + j];
            const float nz = ep.L[row][NEXP + e0 + j];
            ep.L[row][e0 + j] = fmaf(evs[j], softplus_f(nz), lg);
        }
    }
    __syncthreads();

    // ---- per-row top-2 (strict > = first-occurrence tie-break, matches top_k)
    if (tid < TMR) {
        const int r = tid;
        float v1t = -INFINITY, v2t = -INFINITY;
        int i1 = 0, i2 = 0;
#pragma unroll 8
        for (int e = 0; e < NEXP; ++e) {
            const float v = ep.L[r][e];
            if (v > v1t) { v2t = v1t; i2 = i1; v1t = v; i1 = e; }
            else if (v > v2t) { v2t = v; i2 = e; }
        }
        const float z = expf(v2t - v1t);
        const float s = 1.0f + z;
        ep.p1[r] = 1.0f / s;
        ep.p2[r] = z / s;
        ep.i1[r] = i1;
        ep.i2[r] = i2;
        float* oidx = out + (size_t)N * NEXP + (size_t)(rowbase + r) * 2;
        oidx[0] = (float)i1;
        oidx[1] = (float)i2;
    }
    __syncthreads();

    // ---- sparse-softmax rows, coalesced (8 threads per row, 8 cols each)
    {
        const int r = tid >> 3;
        const int g = tid & 7;
        const float pa = ep.p1[r], pb = ep.p2[r];
        const int i1 = ep.i1[r], i2 = ep.i2[r];
        float* orow = out + (size_t)(rowbase + r) * NEXP;
#pragma unroll
        for (int t = 0; t < 2; ++t) {
            const int e0 = g * 8 + t * 4;
            float4 o;
            o.x = (e0 + 0 == i1) ? pa : ((e0 + 0 == i2) ? pb : 0.0f);
            o.y = (e0 + 1 == i1) ? pa : ((e0 + 1 == i2) ? pb : 0.0f);
            o.z = (e0 + 2 == i1) ? pa : ((e0 + 2 == i2) ? pb : 0.0f);
            o.w = (e0 + 3 == i1) ? pa : ((e0 + 3 == i2) ? pb : 0.0f);
            *(float4*)&orow[e0] = o;
        }
    }
}

// ---------------- fallback: verified fp32 kernel from R1 (TM=64) ------------
#define BK 32
#define XS_STRIDE (TM + 4)
#define WS_STRIDE (128 + 4)

__global__ __launch_bounds__(256, 2)
void noisy_topk_router_kernel(const float* __restrict__ x,
                              const float* __restrict__ Wr,
                              const float* __restrict__ br,
                              const float* __restrict__ Wn,
                              const float* __restrict__ bn,
                              const float* __restrict__ eps,
                              float* __restrict__ out,
                              int N, int D) {
    __shared__ union alignas(16) {
        struct {
            float Xs[BK][XS_STRIDE];
            float Ws[BK][WS_STRIDE];
        } st;
        float L[TM][L_STRIDE];
    } sm;
    __shared__ float p1s[TM], p2s[TM];
    __shared__ int   i1s[TM], i2s[TM];

    const int tid = threadIdx.x;
    const int rowbase = blockIdx.x * TM;
    const int r0 = (tid >> 5) * 8;
    const int c0 = (tid & 31) * 4;

    float acc[8][4];
#pragma unroll
    for (int i = 0; i < 8; ++i)
#pragma unroll
        for (int j = 0; j < 4; ++j) acc[i][j] = 0.0f;

    const int q  = tid & 7;
    const int rr = tid >> 3;

    for (int k0 = 0; k0 < D; k0 += BK) {
#pragma unroll
        for (int i = 0; i < 2; ++i) {
            const int row = rr + 32 * i;
            const float4 xv = *(const float4*)&x[(size_t)(rowbase + row) * D + k0 + q * 4];
            sm.st.Xs[q * 4 + 0][row] = xv.x;
            sm.st.Xs[q * 4 + 1][row] = xv.y;
            sm.st.Xs[q * 4 + 2][row] = xv.z;
            sm.st.Xs[q * 4 + 3][row] = xv.w;
            const float4 wv = *(const float4*)&Wr[(size_t)row * D + k0 + q * 4];
            sm.st.Ws[q * 4 + 0][row] = wv.x;
            sm.st.Ws[q * 4 + 1][row] = wv.y;
            sm.st.Ws[q * 4 + 2][row] = wv.z;
            sm.st.Ws[q * 4 + 3][row] = wv.w;
            const float4 nv = *(const float4*)&Wn[(size_t)row * D + k0 + q * 4];
            sm.st.Ws[q * 4 + 0][NEXP + row] = nv.x;
            sm.st.Ws[q * 4 + 1][NEXP + row] = nv.y;
            sm.st.Ws[q * 4 + 2][NEXP + row] = nv.z;
            sm.st.Ws[q * 4 + 3][NEXP + row] = nv.w;
        }
        __syncthreads();
#pragma unroll 4
        for (int kk = 0; kk < BK; ++kk) {
            const float4 xa = *(const float4*)&sm.st.Xs[kk][r0];
            const float4 xb = *(const float4*)&sm.st.Xs[kk][r0 + 4];
            const float4 wv = *(const float4*)&sm.st.Ws[kk][c0];
            const float xs[8] = {xa.x, xa.y, xa.z, xa.w, xb.x, xb.y, xb.z, xb.w};
            const float ws[4] = {wv.x, wv.y, wv.z, wv.w};
#pragma unroll
            for (int i = 0; i < 8; ++i)
#pragma unroll
                for (int j = 0; j < 4; ++j)
                    acc[i][j] = fmaf(xs[i], ws[j], acc[i][j]);
        }
        __syncthreads();
    }
    {
        const float4 bv = (c0 < NEXP) ? *(const float4*)&br[c0]
                                      : *(const float4*)&bn[c0 - NEXP];
#pragma unroll
        for (int i = 0; i < 8; ++i) {
            float4 o;
            o.x = acc[i][0] + bv.x;
            o.y = acc[i][1] + bv.y;
            o.z = acc[i][2] + bv.z;
            o.w = acc[i][3] + bv.w;
            *(float4*)&sm.L[r0 + i][c0] = o;
        }
    }
    __syncthreads();
#pragma unroll
    for (int t = 0; t < 4; ++t) {
        const int f   = tid * 4 + t * 1024;
        const int row = f >> 6;
        const int e0  = f & 63;
        const float4 ev = *(const float4*)&eps[(size_t)(rowbase + row) * NEXP + e0];
        const float evs[4] = {ev.x, ev.y, ev.z, ev.w};
#pragma unroll
        for (int j = 0; j < 4; ++j) {
            const float lg = sm.L[row][e0 + j];
            const float nz = sm.L[row][NEXP + e0 + j];
            sm.L[row][e0 + j] = fmaf(evs[j], softplus_f(nz), lg);
        }
    }
    __syncthreads();
    if (tid < TM) {
        const int r = tid;
        float v1 = -INFINITY, v2 = -INFINITY;
        int i1 = 0, i2 = 0;
#pragma unroll 8
        for (int e = 0; e < NEXP; ++e) {
            const float v = sm.L[r][e];
            if (v > v1) { v2 = v1; i2 = i1; v1 = v; i1 = e; }
            else if (v > v2) { v2 = v; i2 = e; }
        }
        const float z = expf(v2 - v1);
        const float s = 1.0f + z;
        p1s[r] = 1.0f / s;
        p2s[r] = z / s;
        i1s[r] = i1;
        i2s[r] = i2;
        float* oidx = out + (size_t)N * NEXP + (size_t)(rowbase + r) * 2;
        oidx[0] = (float)i1;
        oidx[1] = (float)i2;
    }
    __syncthreads();
    {
        const int r = tid >> 2;
        const int g = tid & 3;
        const float pa = p1s[r], pb = p2s[r];
        const int i1 = i1s[r], i2 = i2s[r];
        float* orow = out + (size_t)(rowbase + r) * NEXP;
#pragma unroll
        for (int t = 0; t < 4; ++t) {
            const int e0 = g * 16 + t * 4;
            float4 o;
            o.x = (e0 + 0 == i1) ? pa : ((e0 + 0 == i2) ? pb : 0.0f);
            o.y = (e0 + 1 == i1) ? pa : ((e0 + 1 == i2) ? pb : 0.0f);
            o.z = (e0 + 2 == i1) ? pa : ((e0 + 2 == i2) ? pb : 0.0f);
            o.w = (e0 + 3 == i1) ? pa : ((e0 + 3 == i2) ? pb : 0.0f);
            *(float4*)&orow[e0] = o;
        }
    }
}

extern "C" void kernel_launch(void* const* d_in, const int* in_sizes, int n_in,
                              void* d_out, int out_size, void* d_ws, size_t ws_size,
                              hipStream_t stream) {
    const float* x   = (const float*)d_in[0];
    const float* Wr  = (const float*)d_in[1];
    const float* br  = (const float*)d_in[2];
    const float* Wn  = (const float*)d_in[3];
    const float* bn  = (const float*)d_in[4];
    const float* eps = (const float*)d_in[5];
    float* out = (float*)d_out;

    const int E = in_sizes[2];
    const int D = in_sizes[1] / E;
    const int N = in_sizes[0] / D;

    const size_t ws_needed = (size_t)128 * D * 2 * sizeof(f16);
    const bool fast = (E == 64) && (D == 2048) && (N % TMR == 0) && (ws_size >= ws_needed);

    if (fast) {
        const int pre_threads = 128 * (D / 8);
        wsplit_kernel<<<(pre_threads + 255) / 256, 256, 0, stream>>>(Wr, Wn, (f16*)d_ws, D);
        router_mfma_kernel<<<N / TMR, 256, 0, stream>>>(x, (const f16*)d_ws, br, bn, eps, out, N, D);
    } else {
        noisy_topk_router_kernel<<<N / TM, 256, 0, stream>>>(x, Wr, br, Wn, bn, eps, out, N, D);
    }
}